// Round 2
// baseline (719.962 us; speedup 1.0000x reference)
//
#include <hip/hip_runtime.h>

#define NDIM 256
#define NC 129          // rfft output columns
#define NPAIRS 256

// W16[m] = exp(-2*pi*i*m/16): C16 = cos, S16 = -sin
__device__ constexpr float C16[16] = {
    1.0f,  0.9238795325112867f,  0.7071067811865476f,  0.3826834323650898f,
    0.0f, -0.3826834323650898f, -0.7071067811865476f, -0.9238795325112867f,
   -1.0f, -0.9238795325112867f, -0.7071067811865476f, -0.3826834323650898f,
    0.0f,  0.3826834323650898f,  0.7071067811865476f,  0.9238795325112867f };
__device__ constexpr float S16[16] = {
    0.0f, -0.3826834323650898f, -0.7071067811865476f, -0.9238795325112867f,
   -1.0f, -0.9238795325112867f, -0.7071067811865476f, -0.3826834323650898f,
    0.0f,  0.3826834323650898f,  0.7071067811865476f,  0.9238795325112867f,
    1.0f,  0.9238795325112867f,  0.7071067811865476f,  0.3826834323650898f };

// twiddle W256^m = exp(-2*pi*i*m/256) via HW sin/cos (revolution input, exact arg)
__device__ __forceinline__ void tw256(int m, float& cw, float& sw) {
  const float x = -(float)m * (1.0f / 256.0f);
  cw = __builtin_amdgcn_cosf(x);
  sw = __builtin_amdgcn_sinf(x);
}

// ---------------- Stage 1: row-wise rfft (axis -1) per image -----------------
// 2 blocks per image; 256 threads; each block does 8 row-groups of 16 rows.
__global__ __launch_bounds__(256) void stage1_kernel(
    const float* __restrict__ a, const float* __restrict__ b,
    float2* __restrict__ s1, int p0, int pc) {
  __shared__ float Bre[16 * 272];  // [lr]*272 + [n2]*17 + [k1]
  __shared__ float Bim[16 * 272];
  const int t = threadIdx.x;
  const int lr = t >> 4;
  const int sub = t & 15;
  const int li = blockIdx.x >> 1;
  const int half = blockIdx.x & 1;
  const float* src = (li < pc) ? (a + (size_t)(p0 + li) * (NDIM * NDIM))
                               : (b + (size_t)(p0 + li - pc) * (NDIM * NDIM));
  float2* dst = s1 + (size_t)li * (NDIM * NC);

  for (int g = half * 8; g < half * 8 + 8; ++g) {
    const int row = g * 16 + lr;
    // phase 1: thread (row, n2=sub): A[k1] = sum_n1 x[16*n1+n2] W16^{n1 k1}
    float xr[16];
    const float* xrow = src + row * NDIM + sub;
#pragma unroll
    for (int n1 = 0; n1 < 16; ++n1) xr[n1] = xrow[16 * n1];
#pragma unroll
    for (int k1 = 0; k1 < 16; ++k1) {
      float sr = 0.f, si = 0.f;
#pragma unroll
      for (int n = 0; n < 16; ++n) {
        const int m = (n * k1) & 15;
        sr += xr[n] * C16[m];
        si += xr[n] * S16[m];
      }
      float cw, sw; tw256(sub * k1, cw, sw);
      Bre[lr * 272 + sub * 17 + k1] = sr * cw - si * sw;
      Bim[lr * 272 + sub * 17 + k1] = sr * sw + si * cw;
    }
    __syncthreads();
    // phase 2: thread (row, k1=sub): F[k1+16*k2] = sum_n2 B[n2][k1] W16^{n2 k2}
    float br[16], bi[16];
#pragma unroll
    for (int n2 = 0; n2 < 16; ++n2) {
      br[n2] = Bre[lr * 272 + n2 * 17 + sub];
      bi[n2] = Bim[lr * 272 + n2 * 17 + sub];
    }
    float2* drow = dst + row * NC;
#pragma unroll
    for (int k2 = 0; k2 < 16; ++k2) {
      float fr = 0.f, fi = 0.f;
#pragma unroll
      for (int n2 = 0; n2 < 16; ++n2) {
        const int m = (n2 * k2) & 15;
        fr += br[n2] * C16[m] - bi[n2] * S16[m];
        fi += br[n2] * S16[m] + bi[n2] * C16[m];
      }
      const int k = sub + 16 * k2;
      if (k <= 128) drow[k] = make_float2(fr, fi);
    }
    __syncthreads();
  }
}

// ------- Stage 2: column-wise 256-pt FFT + ring accumulation per pair --------
// block = (pair lp, column group g of 16 cols); 256 threads, col = t&15.
__global__ __launch_bounds__(256, 3) void stage2_kernel(
    const float2* __restrict__ s1, const int* __restrict__ rr,
    float* __restrict__ partial, int p0, int pc) {
  __shared__ float Bre[16 * 290];     // [col]*290 + [n2]*17 + [k1]; 290%32==2
  __shared__ float Bim[16 * 290];
  __shared__ float binacc[4][3][132]; // per-wave bins
  const int t = threadIdx.x;
  const int col = t & 15;
  const int sub = t >> 4;
  const int wv = t >> 6;
  const int blk = blockIdx.x;
  const int lp = blk / 9;
  const int g = blk % 9;
  const int c0 = g * 16;
  const int W = (c0 + 16 <= NC) ? 16 : (NC - c0);
  const bool active = (col < W);
  const int cc = active ? (c0 + col) : (NC - 1);

  for (int i = t; i < 4 * 3 * 132; i += 256) ((float*)binacc)[i] = 0.f;

  const float2* simgA = s1 + (size_t)lp * (NDIM * NC);
  const float2* simgB = s1 + (size_t)(lp + pc) * (NDIM * NC);

  // ================= image A: column FFT, keep result in registers ==========
  float far[16], fai[16];
  {
    float yr[16], yi[16];
#pragma unroll
    for (int n1 = 0; n1 < 16; ++n1) {
      const float2 v = simgA[(16 * n1 + sub) * NC + cc];
      yr[n1] = v.x; yi[n1] = v.y;
    }
#pragma unroll
    for (int k1 = 0; k1 < 16; ++k1) {
      float sr = 0.f, si = 0.f;
#pragma unroll
      for (int n = 0; n < 16; ++n) {
        const int m = (n * k1) & 15;
        sr += yr[n] * C16[m] - yi[n] * S16[m];
        si += yr[n] * S16[m] + yi[n] * C16[m];
      }
      float cw, sw; tw256(sub * k1, cw, sw);
      Bre[col * 290 + sub * 17 + k1] = sr * cw - si * sw;
      Bim[col * 290 + sub * 17 + k1] = sr * sw + si * cw;
    }
    __syncthreads();
    float br[16], bi[16];
#pragma unroll
    for (int n2 = 0; n2 < 16; ++n2) {
      br[n2] = Bre[col * 290 + n2 * 17 + sub];
      bi[n2] = Bim[col * 290 + n2 * 17 + sub];
    }
#pragma unroll
    for (int k2 = 0; k2 < 16; ++k2) {
      float fr = 0.f, fi = 0.f;
#pragma unroll
      for (int n2 = 0; n2 < 16; ++n2) {
        const int m = (n2 * k2) & 15;
        fr += br[n2] * C16[m] - bi[n2] * S16[m];
        fi += br[n2] * S16[m] + bi[n2] * C16[m];
      }
      far[k2] = fr; fai[k2] = fi;
    }
    __syncthreads();
  }

  // ================= image B: column FFT + products + ring bins =============
  {
    int bins[16];
#pragma unroll
    for (int k2 = 0; k2 < 16; ++k2) bins[k2] = rr[(sub + 16 * k2) * NC + cc];
    float yr[16], yi[16];
#pragma unroll
    for (int n1 = 0; n1 < 16; ++n1) {
      const float2 v = simgB[(16 * n1 + sub) * NC + cc];
      yr[n1] = v.x; yi[n1] = v.y;
    }
#pragma unroll
    for (int k1 = 0; k1 < 16; ++k1) {
      float sr = 0.f, si = 0.f;
#pragma unroll
      for (int n = 0; n < 16; ++n) {
        const int m = (n * k1) & 15;
        sr += yr[n] * C16[m] - yi[n] * S16[m];
        si += yr[n] * S16[m] + yi[n] * C16[m];
      }
      float cw, sw; tw256(sub * k1, cw, sw);
      Bre[col * 290 + sub * 17 + k1] = sr * cw - si * sw;
      Bim[col * 290 + sub * 17 + k1] = sr * sw + si * cw;
    }
    __syncthreads();
    float br[16], bi[16];
#pragma unroll
    for (int n2 = 0; n2 < 16; ++n2) {
      br[n2] = Bre[col * 290 + n2 * 17 + sub];
      bi[n2] = Bim[col * 290 + n2 * 17 + sub];
    }
#pragma unroll
    for (int k2 = 0; k2 < 16; ++k2) {
      float fr = 0.f, fi = 0.f;
#pragma unroll
      for (int n2 = 0; n2 < 16; ++n2) {
        const int m = (n2 * k2) & 15;
        fr += br[n2] * C16[m] - bi[n2] * S16[m];
        fi += br[n2] * S16[m] + bi[n2] * C16[m];
      }
      if (active) {
        const float pa = far[k2] * far[k2] + fai[k2] * fai[k2];
        const float pb = fr * fr + fi * fi;
        const float nm = far[k2] * fr + fai[k2] * fi;
        atomicAdd(&binacc[wv][0][bins[k2]], pa);
        atomicAdd(&binacc[wv][1][bins[k2]], pb);
        atomicAdd(&binacc[wv][2][bins[k2]], nm);
      }
    }
    __syncthreads();
  }

  // per-(pair, group) partial ring sums (deterministic layout, no global atomics)
  float* pdst = partial + (size_t)((p0 + lp) * 9 + g) * (3 * NC);
  for (int i = t; i < 3 * NC; i += 256) {
    const int q = i / NC, bin = i % NC;
    pdst[i] = binacc[0][q][bin] + binacc[1][q][bin] +
              binacc[2][q][bin] + binacc[3][q][bin];
  }
}

// ---------------- Stage 3a: per-pair FRC partial sum (double) ----------------
__global__ __launch_bounds__(128) void stage3a_kernel(
    const float* __restrict__ partial, double* __restrict__ pairsum) {
  const int pair = blockIdx.x;
  const int t = threadIdx.x;  // 128 threads; bins 1..126 active
  double v = 0.0;
  if (t >= 1 && t <= 126) {
    float na = 0.f, nb = 0.f, nm = 0.f;
    for (int g = 0; g < 9; ++g) {
      const float* p = partial + (size_t)(pair * 9 + g) * (3 * NC);
      na += p[t];
      nb += p[NC + t];
      nm += p[2 * NC + t];
    }
    const double den = fmax(sqrt((double)na) * sqrt((double)nb), 1e-4);
    v = (double)nm / den;
  }
  __shared__ double sd[128];
  sd[t] = v;
  __syncthreads();
  for (int s = 64; s > 0; s >>= 1) {
    if (t < s) sd[t] += sd[t + s];
    __syncthreads();
  }
  if (t == 0) pairsum[pair] = sd[0];
}

// ---------------- Stage 3b: final mean ---------------------------------------
__global__ __launch_bounds__(256) void stage3b_kernel(
    const double* __restrict__ pairsum, float* __restrict__ out) {
  const int t = threadIdx.x;
  __shared__ double sd[256];
  sd[t] = pairsum[t];
  __syncthreads();
  for (int s = 128; s > 0; s >>= 1) {
    if (t < s) sd[t] += sd[t + s];
    __syncthreads();
  }
  if (t == 0) out[0] = (float)(sd[0] / 32256.0);  // 256 pairs * 126 bins
}

extern "C" void kernel_launch(void* const* d_in, const int* in_sizes, int n_in,
                              void* d_out, int out_size, void* d_ws, size_t ws_size,
                              hipStream_t stream) {
  const float* a = (const float*)d_in[0];
  const float* b = (const float*)d_in[1];
  const int* rr = (const int*)d_in[2];
  float* out = (float*)d_out;

  char* ws = (char*)d_ws;
  const size_t partial_bytes = (size_t)NPAIRS * 9 * 3 * NC * sizeof(float);
  size_t off = (partial_bytes + 255) & ~(size_t)255;
  float* partial = (float*)ws;
  double* pairsum = (double*)(ws + off);
  off += ((size_t)NPAIRS * sizeof(double) + 255) & ~(size_t)255;
  float2* s1 = (float2*)(ws + off);

  const size_t bytes_per_img = (size_t)NDIM * NC * sizeof(float2);
  const size_t s1_avail = (ws_size > off) ? (ws_size - off) : 0;
  int cap = (int)(s1_avail / bytes_per_img);
  int P = cap / 2;
  if (P > NPAIRS) P = NPAIRS;
  if (P < 1) P = 1;  // assume workspace holds at least one pair

  for (int p0 = 0; p0 < NPAIRS; p0 += P) {
    const int pc = (NPAIRS - p0 < P) ? (NPAIRS - p0) : P;
    hipLaunchKernelGGL(stage1_kernel, dim3(4 * pc), dim3(256), 0, stream,
                       a, b, s1, p0, pc);
    hipLaunchKernelGGL(stage2_kernel, dim3(pc * 9), dim3(256), 0, stream,
                       s1, rr, partial, p0, pc);
  }
  hipLaunchKernelGGL(stage3a_kernel, dim3(NPAIRS), dim3(128), 0, stream,
                     partial, pairsum);
  hipLaunchKernelGGL(stage3b_kernel, dim3(1), dim3(256), 0, stream,
                     pairsum, out);
}

// Round 3
// 247.202 us; speedup vs baseline: 2.9124x; 2.9124x over previous
//
#include <hip/hip_runtime.h>

#define NDIM 256
#define NC 129          // rfft output columns
#define NPAIRS 256

// twiddle W256^m = exp(-2*pi*i*m/256) via HW sin/cos (revolution input, exact arg)
__device__ __forceinline__ void tw256(int m, float& cw, float& sw) {
  const float x = -(float)m * (1.0f / 256.0f);
  cw = __builtin_amdgcn_cosf(x);
  sw = __builtin_amdgcn_sinf(x);
}

// In-register 16-point FFT (DIT radix-4), natural order in/out.
// X[k] = sum_n x[n] * W16^{nk}, W16 = exp(-2*pi*i/16).
__device__ __forceinline__ void fft16(float xr[16], float xi[16]) {
  const float c1 = 0.9238795325112867f, s1 = 0.3826834323650898f;
  const float h  = 0.7071067811865476f;
  float yr[4][4], yi[4][4];  // y[r][q]: DFT4 over n-groups
#pragma unroll
  for (int r = 0; r < 4; ++r) {
    const float ar = xr[r],      ai = xi[r];
    const float br = xr[r + 4],  bi = xi[r + 4];
    const float cr = xr[r + 8],  ci = xi[r + 8];
    const float dr = xr[r + 12], di = xi[r + 12];
    const float t0r = ar + cr, t0i = ai + ci;
    const float t1r = ar - cr, t1i = ai - ci;
    const float t2r = br + dr, t2i = bi + di;
    const float t3r = br - dr, t3i = bi - di;
    yr[r][0] = t0r + t2r; yi[r][0] = t0i + t2i;
    yr[r][1] = t1r + t3i; yi[r][1] = t1i - t3r;   // t1 - i*t3
    yr[r][2] = t0r - t2r; yi[r][2] = t0i - t2i;
    yr[r][3] = t1r - t3i; yi[r][3] = t1i + t3r;   // t1 + i*t3
  }
  // z_r = y[r][q] * W16^{rq}; X[q+4p] = DFT4 over r (index p)
#pragma unroll
  for (int q = 0; q < 4; ++q) {
    const float z0r = yr[0][q], z0i = yi[0][q];
    float z1r, z1i, z2r, z2i, z3r, z3i;
    if (q == 0) {
      z1r = yr[1][0]; z1i = yi[1][0];
      z2r = yr[2][0]; z2i = yi[2][0];
      z3r = yr[3][0]; z3i = yi[3][0];
    } else if (q == 1) {
      z1r =  c1 * yr[1][1] + s1 * yi[1][1]; z1i =  c1 * yi[1][1] - s1 * yr[1][1]; // W^1
      z2r =   h * yr[2][1] +  h * yi[2][1]; z2i =   h * yi[2][1] -  h * yr[2][1]; // W^2
      z3r =  s1 * yr[3][1] + c1 * yi[3][1]; z3i =  s1 * yi[3][1] - c1 * yr[3][1]; // W^3
    } else if (q == 2) {
      z1r =   h * yr[1][2] +  h * yi[1][2]; z1i =   h * yi[1][2] -  h * yr[1][2]; // W^2
      z2r =  yi[2][2];                      z2i = -yr[2][2];                      // W^4=-i
      z3r =  -h * yr[3][2] +  h * yi[3][2]; z3i =  -h * yi[3][2] -  h * yr[3][2]; // W^6
    } else {
      z1r =  s1 * yr[1][3] + c1 * yi[1][3]; z1i =  s1 * yi[1][3] - c1 * yr[1][3]; // W^3
      z2r =  -h * yr[2][3] +  h * yi[2][3]; z2i =  -h * yi[2][3] -  h * yr[2][3]; // W^6
      z3r = -c1 * yr[3][3] - s1 * yi[3][3]; z3i = -c1 * yi[3][3] + s1 * yr[3][3]; // W^9
    }
    const float u0r = z0r + z2r, u0i = z0i + z2i;
    const float u1r = z0r - z2r, u1i = z0i - z2i;
    const float u2r = z1r + z3r, u2i = z1i + z3i;
    const float u3r = z1r - z3r, u3i = z1i - z3i;
    xr[q]      = u0r + u2r; xi[q]      = u0i + u2i;
    xr[q + 4]  = u1r + u3i; xi[q + 4]  = u1i - u3r;  // u1 - i*u3
    xr[q + 8]  = u0r - u2r; xi[q + 8]  = u0i - u2i;
    xr[q + 12] = u1r - u3i; xi[q + 12] = u1i + u3r;  // u1 + i*u3
  }
}

// ---------------- Stage 1: row-wise rfft (axis -1) per image -----------------
// 2 blocks per image; 256 threads; each block does 8 row-groups of 16 rows.
__global__ __launch_bounds__(256) void stage1_kernel(
    const float* __restrict__ a, const float* __restrict__ b,
    float2* __restrict__ s1, int p0, int pc) {
  __shared__ float Bre[16 * 272];  // [lr]*272 + [n2]*17 + [k1]
  __shared__ float Bim[16 * 272];
  const int t = threadIdx.x;
  const int lr = t >> 4;
  const int sub = t & 15;
  const int li = blockIdx.x >> 1;
  const int half = blockIdx.x & 1;
  const float* src = (li < pc) ? (a + (size_t)(p0 + li) * (NDIM * NDIM))
                               : (b + (size_t)(p0 + li - pc) * (NDIM * NDIM));
  float2* dst = s1 + (size_t)li * (NDIM * NC);

  // hoisted twiddles W256^{sub*k1} (reused by all 16 row-groups)
  float cw16[16], sw16[16];
#pragma unroll
  for (int k1 = 0; k1 < 16; ++k1) tw256(sub * k1, cw16[k1], sw16[k1]);

  for (int g = half * 8; g < half * 8 + 8; ++g) {
    const int row = g * 16 + lr;
    // phase 1: thread (row, n2=sub): A[k1] = sum_n1 x[16*n1+n2] W16^{n1 k1}
    float xr[16], xi[16];
    const float* xrow = src + row * NDIM + sub;
#pragma unroll
    for (int n1 = 0; n1 < 16; ++n1) { xr[n1] = xrow[16 * n1]; xi[n1] = 0.f; }
    fft16(xr, xi);
#pragma unroll
    for (int k1 = 0; k1 < 16; ++k1) {
      Bre[lr * 272 + sub * 17 + k1] = xr[k1] * cw16[k1] - xi[k1] * sw16[k1];
      Bim[lr * 272 + sub * 17 + k1] = xr[k1] * sw16[k1] + xi[k1] * cw16[k1];
    }
    __syncthreads();
    // phase 2: thread (row, k1=sub): F[k1+16*k2] = sum_n2 B[n2][k1] W16^{n2 k2}
    float br[16], bi[16];
#pragma unroll
    for (int n2 = 0; n2 < 16; ++n2) {
      br[n2] = Bre[lr * 272 + n2 * 17 + sub];
      bi[n2] = Bim[lr * 272 + n2 * 17 + sub];
    }
    fft16(br, bi);
    float2* drow = dst + row * NC;
#pragma unroll
    for (int k2 = 0; k2 < 16; ++k2) {
      const int k = sub + 16 * k2;
      if (k <= 128) drow[k] = make_float2(br[k2], bi[k2]);
    }
    __syncthreads();
  }
}

// ------- Stage 2: column-wise 256-pt FFT + ring accumulation per pair --------
// block = (pair lp, column group g of 16 cols); 256 threads, col = t&15.
__global__ __launch_bounds__(256) void stage2_kernel(
    const float2* __restrict__ s1, const int* __restrict__ rr,
    float* __restrict__ partial, int p0, int pc) {
  __shared__ float Bre[16 * 290];     // [col]*290 + [n2]*17 + [k1]; 290%32==2
  __shared__ float Bim[16 * 290];
  __shared__ float binacc[4][3][132]; // per-wave bins
  const int t = threadIdx.x;
  const int col = t & 15;
  const int sub = t >> 4;
  const int wv = t >> 6;
  const int blk = blockIdx.x;
  const int lp = blk / 9;
  const int g = blk % 9;
  const int c0 = g * 16;
  const int W = (c0 + 16 <= NC) ? 16 : (NC - c0);
  const bool active = (col < W);
  const int cc = active ? (c0 + col) : (NC - 1);

  for (int i = t; i < 4 * 3 * 132; i += 256) ((float*)binacc)[i] = 0.f;

  const float2* simgA = s1 + (size_t)lp * (NDIM * NC);
  const float2* simgB = s1 + (size_t)(lp + pc) * (NDIM * NC);

  // ================= image A: column FFT, keep result in registers ==========
  float far[16], fai[16];
  {
    float xr[16], xi[16];
#pragma unroll
    for (int n1 = 0; n1 < 16; ++n1) {
      const float2 v = simgA[(16 * n1 + sub) * NC + cc];
      xr[n1] = v.x; xi[n1] = v.y;
    }
    fft16(xr, xi);
#pragma unroll
    for (int k1 = 0; k1 < 16; ++k1) {
      float cw, sw; tw256(sub * k1, cw, sw);
      Bre[col * 290 + sub * 17 + k1] = xr[k1] * cw - xi[k1] * sw;
      Bim[col * 290 + sub * 17 + k1] = xr[k1] * sw + xi[k1] * cw;
    }
    __syncthreads();
#pragma unroll
    for (int n2 = 0; n2 < 16; ++n2) {
      far[n2] = Bre[col * 290 + n2 * 17 + sub];
      fai[n2] = Bim[col * 290 + n2 * 17 + sub];
    }
    fft16(far, fai);
    __syncthreads();
  }

  // ================= image B: column FFT + products + ring bins =============
  {
    float xr[16], xi[16];
#pragma unroll
    for (int n1 = 0; n1 < 16; ++n1) {
      const float2 v = simgB[(16 * n1 + sub) * NC + cc];
      xr[n1] = v.x; xi[n1] = v.y;
    }
    fft16(xr, xi);
#pragma unroll
    for (int k1 = 0; k1 < 16; ++k1) {
      float cw, sw; tw256(sub * k1, cw, sw);
      Bre[col * 290 + sub * 17 + k1] = xr[k1] * cw - xi[k1] * sw;
      Bim[col * 290 + sub * 17 + k1] = xr[k1] * sw + xi[k1] * cw;
    }
    __syncthreads();
    float br[16], bi[16];
#pragma unroll
    for (int n2 = 0; n2 < 16; ++n2) {
      br[n2] = Bre[col * 290 + n2 * 17 + sub];
      bi[n2] = Bim[col * 290 + n2 * 17 + sub];
    }
    fft16(br, bi);
    if (active) {
      int bins[16];
#pragma unroll
      for (int k2 = 0; k2 < 16; ++k2) bins[k2] = rr[(sub + 16 * k2) * NC + cc];
#pragma unroll
      for (int k2 = 0; k2 < 16; ++k2) {
        const float pa = far[k2] * far[k2] + fai[k2] * fai[k2];
        const float pb = br[k2] * br[k2] + bi[k2] * bi[k2];
        const float nm = far[k2] * br[k2] + fai[k2] * bi[k2];
        atomicAdd(&binacc[wv][0][bins[k2]], pa);
        atomicAdd(&binacc[wv][1][bins[k2]], pb);
        atomicAdd(&binacc[wv][2][bins[k2]], nm);
      }
    }
    __syncthreads();
  }

  // per-(pair, group) partial ring sums (deterministic layout, no global atomics)
  float* pdst = partial + (size_t)((p0 + lp) * 9 + g) * (3 * NC);
  for (int i = t; i < 3 * NC; i += 256) {
    const int q = i / NC, bin = i % NC;
    pdst[i] = binacc[0][q][bin] + binacc[1][q][bin] +
              binacc[2][q][bin] + binacc[3][q][bin];
  }
}

// ---------------- Stage 3a: per-pair FRC partial sum (double) ----------------
__global__ __launch_bounds__(128) void stage3a_kernel(
    const float* __restrict__ partial, double* __restrict__ pairsum) {
  const int pair = blockIdx.x;
  const int t = threadIdx.x;  // 128 threads; bins 1..126 active
  double v = 0.0;
  if (t >= 1 && t <= 126) {
    float na = 0.f, nb = 0.f, nm = 0.f;
    for (int g = 0; g < 9; ++g) {
      const float* p = partial + (size_t)(pair * 9 + g) * (3 * NC);
      na += p[t];
      nb += p[NC + t];
      nm += p[2 * NC + t];
    }
    const double den = fmax(sqrt((double)na) * sqrt((double)nb), 1e-4);
    v = (double)nm / den;
  }
  __shared__ double sd[128];
  sd[t] = v;
  __syncthreads();
  for (int s = 64; s > 0; s >>= 1) {
    if (t < s) sd[t] += sd[t + s];
    __syncthreads();
  }
  if (t == 0) pairsum[pair] = sd[0];
}

// ---------------- Stage 3b: final mean ---------------------------------------
__global__ __launch_bounds__(256) void stage3b_kernel(
    const double* __restrict__ pairsum, float* __restrict__ out) {
  const int t = threadIdx.x;
  __shared__ double sd[256];
  sd[t] = pairsum[t];
  __syncthreads();
  for (int s = 128; s > 0; s >>= 1) {
    if (t < s) sd[t] += sd[t + s];
    __syncthreads();
  }
  if (t == 0) out[0] = (float)(sd[0] / 32256.0);  // 256 pairs * 126 bins
}

extern "C" void kernel_launch(void* const* d_in, const int* in_sizes, int n_in,
                              void* d_out, int out_size, void* d_ws, size_t ws_size,
                              hipStream_t stream) {
  const float* a = (const float*)d_in[0];
  const float* b = (const float*)d_in[1];
  const int* rr = (const int*)d_in[2];
  float* out = (float*)d_out;

  char* ws = (char*)d_ws;
  const size_t partial_bytes = (size_t)NPAIRS * 9 * 3 * NC * sizeof(float);
  size_t off = (partial_bytes + 255) & ~(size_t)255;
  float* partial = (float*)ws;
  double* pairsum = (double*)(ws + off);
  off += ((size_t)NPAIRS * sizeof(double) + 255) & ~(size_t)255;
  float2* s1 = (float2*)(ws + off);

  const size_t bytes_per_img = (size_t)NDIM * NC * sizeof(float2);
  const size_t s1_avail = (ws_size > off) ? (ws_size - off) : 0;
  int cap = (int)(s1_avail / bytes_per_img);
  int P = cap / 2;
  if (P > NPAIRS) P = NPAIRS;
  if (P < 1) P = 1;  // assume workspace holds at least one pair

  for (int p0 = 0; p0 < NPAIRS; p0 += P) {
    const int pc = (NPAIRS - p0 < P) ? (NPAIRS - p0) : P;
    hipLaunchKernelGGL(stage1_kernel, dim3(4 * pc), dim3(256), 0, stream,
                       a, b, s1, p0, pc);
    hipLaunchKernelGGL(stage2_kernel, dim3(pc * 9), dim3(256), 0, stream,
                       s1, rr, partial, p0, pc);
  }
  hipLaunchKernelGGL(stage3a_kernel, dim3(NPAIRS), dim3(128), 0, stream,
                     partial, pairsum);
  hipLaunchKernelGGL(stage3b_kernel, dim3(1), dim3(256), 0, stream,
                     pairsum, out);
}

// Round 4
// 225.584 us; speedup vs baseline: 3.1915x; 1.0958x over previous
//
#include <hip/hip_runtime.h>

#define NDIM 256
#define NC 129          // rfft output columns
#define NPAIRS 256

// twiddle W256^m = exp(-2*pi*i*m/256) via HW sin/cos (revolution input, exact arg)
__device__ __forceinline__ void tw256(int m, float& cw, float& sw) {
  const float x = -(float)m * (1.0f / 256.0f);
  cw = __builtin_amdgcn_cosf(x);
  sw = __builtin_amdgcn_sinf(x);
}

// In-register 16-point FFT (DIT radix-4), natural order in/out.
// X[k] = sum_n x[n] * W16^{nk}, W16 = exp(-2*pi*i/16).
__device__ __forceinline__ void fft16(float xr[16], float xi[16]) {
  const float c1 = 0.9238795325112867f, s1 = 0.3826834323650898f;
  const float h  = 0.7071067811865476f;
  float yr[4][4], yi[4][4];  // y[r][q]: DFT4 over n-groups
#pragma unroll
  for (int r = 0; r < 4; ++r) {
    const float ar = xr[r],      ai = xi[r];
    const float br = xr[r + 4],  bi = xi[r + 4];
    const float cr = xr[r + 8],  ci = xi[r + 8];
    const float dr = xr[r + 12], di = xi[r + 12];
    const float t0r = ar + cr, t0i = ai + ci;
    const float t1r = ar - cr, t1i = ai - ci;
    const float t2r = br + dr, t2i = bi + di;
    const float t3r = br - dr, t3i = bi - di;
    yr[r][0] = t0r + t2r; yi[r][0] = t0i + t2i;
    yr[r][1] = t1r + t3i; yi[r][1] = t1i - t3r;   // t1 - i*t3
    yr[r][2] = t0r - t2r; yi[r][2] = t0i - t2i;
    yr[r][3] = t1r - t3i; yi[r][3] = t1i + t3r;   // t1 + i*t3
  }
  // z_r = y[r][q] * W16^{rq}; X[q+4p] = DFT4 over r (index p)
#pragma unroll
  for (int q = 0; q < 4; ++q) {
    const float z0r = yr[0][q], z0i = yi[0][q];
    float z1r, z1i, z2r, z2i, z3r, z3i;
    if (q == 0) {
      z1r = yr[1][0]; z1i = yi[1][0];
      z2r = yr[2][0]; z2i = yi[2][0];
      z3r = yr[3][0]; z3i = yi[3][0];
    } else if (q == 1) {
      z1r =  c1 * yr[1][1] + s1 * yi[1][1]; z1i =  c1 * yi[1][1] - s1 * yr[1][1]; // W^1
      z2r =   h * yr[2][1] +  h * yi[2][1]; z2i =   h * yi[2][1] -  h * yr[2][1]; // W^2
      z3r =  s1 * yr[3][1] + c1 * yi[3][1]; z3i =  s1 * yi[3][1] - c1 * yr[3][1]; // W^3
    } else if (q == 2) {
      z1r =   h * yr[1][2] +  h * yi[1][2]; z1i =   h * yi[1][2] -  h * yr[1][2]; // W^2
      z2r =  yi[2][2];                      z2i = -yr[2][2];                      // W^4=-i
      z3r =  -h * yr[3][2] +  h * yi[3][2]; z3i =  -h * yi[3][2] -  h * yr[3][2]; // W^6
    } else {
      z1r =  s1 * yr[1][3] + c1 * yi[1][3]; z1i =  s1 * yi[1][3] - c1 * yr[1][3]; // W^3
      z2r =  -h * yr[2][3] +  h * yi[2][3]; z2i =  -h * yi[2][3] -  h * yr[2][3]; // W^6
      z3r = -c1 * yr[3][3] - s1 * yi[3][3]; z3i = -c1 * yi[3][3] + s1 * yr[3][3]; // W^9
    }
    const float u0r = z0r + z2r, u0i = z0i + z2i;
    const float u1r = z0r - z2r, u1i = z0i - z2i;
    const float u2r = z1r + z3r, u2i = z1i + z3i;
    const float u3r = z1r - z3r, u3i = z1i - z3i;
    xr[q]      = u0r + u2r; xi[q]      = u0i + u2i;
    xr[q + 4]  = u1r + u3i; xi[q + 4]  = u1i - u3r;  // u1 - i*u3
    xr[q + 8]  = u0r - u2r; xi[q + 8]  = u0i - u2i;
    xr[q + 12] = u1r - u3i; xi[q + 12] = u1i + u3r;  // u1 + i*u3
  }
}

// ---------------- Stage 1: row-wise rfft (axis -1) per image -----------------
// 2 blocks per image; 256 threads; each block does 8 row-groups of 16 rows.
__global__ __launch_bounds__(256) void stage1_kernel(
    const float* __restrict__ a, const float* __restrict__ b,
    float2* __restrict__ s1, int p0, int pc) {
  __shared__ float Bre[16 * 272];  // [lr]*272 + [n2]*17 + [k1]
  __shared__ float Bim[16 * 272];
  const int t = threadIdx.x;
  const int lr = t >> 4;
  const int sub = t & 15;
  const int li = blockIdx.x >> 1;
  const int half = blockIdx.x & 1;
  const float* src = (li < pc) ? (a + (size_t)(p0 + li) * (NDIM * NDIM))
                               : (b + (size_t)(p0 + li - pc) * (NDIM * NDIM));
  float2* dst = s1 + (size_t)li * (NDIM * NC);

  // hoisted twiddles W256^{sub*k1} (reused by all 16 row-groups)
  float cw16[16], sw16[16];
#pragma unroll
  for (int k1 = 0; k1 < 16; ++k1) tw256(sub * k1, cw16[k1], sw16[k1]);

  for (int g = half * 8; g < half * 8 + 8; ++g) {
    const int row = g * 16 + lr;
    // phase 1: thread (row, n2=sub): A[k1] = sum_n1 x[16*n1+n2] W16^{n1 k1}
    float xr[16], xi[16];
    const float* xrow = src + row * NDIM + sub;
#pragma unroll
    for (int n1 = 0; n1 < 16; ++n1) { xr[n1] = xrow[16 * n1]; xi[n1] = 0.f; }
    fft16(xr, xi);
#pragma unroll
    for (int k1 = 0; k1 < 16; ++k1) {
      Bre[lr * 272 + sub * 17 + k1] = xr[k1] * cw16[k1] - xi[k1] * sw16[k1];
      Bim[lr * 272 + sub * 17 + k1] = xr[k1] * sw16[k1] + xi[k1] * cw16[k1];
    }
    __syncthreads();
    // phase 2: thread (row, k1=sub): F[k1+16*k2] = sum_n2 B[n2][k1] W16^{n2 k2}
    float br[16], bi[16];
#pragma unroll
    for (int n2 = 0; n2 < 16; ++n2) {
      br[n2] = Bre[lr * 272 + n2 * 17 + sub];
      bi[n2] = Bim[lr * 272 + n2 * 17 + sub];
    }
    fft16(br, bi);
    float2* drow = dst + row * NC;
#pragma unroll
    for (int k2 = 0; k2 < 16; ++k2) {
      const int k = sub + 16 * k2;
      if (k <= 128) drow[k] = make_float2(br[k2], bi[k2]);
    }
    __syncthreads();
  }
}

// ------- Stage 2: column-wise 256-pt FFT + ring accumulation per pair --------
// block = (pair lp, column group g of 16 cols); 256 threads, col = t&15.
__global__ __launch_bounds__(256) void stage2_kernel(
    const float2* __restrict__ s1, const int* __restrict__ rr,
    float* __restrict__ partial, int p0, int pc) {
  __shared__ float Bre[16 * 290];     // [col]*290 + [n2]*17 + [k1]; 290%32==2
  __shared__ float Bim[16 * 290];
  __shared__ float binacc[8][3][132]; // 8 copies indexed by col&7 (decorrelate)
  const int t = threadIdx.x;
  const int col = t & 15;
  const int sub = t >> 4;
  const int blk = blockIdx.x;
  const int lp = blk / 9;
  const int g = blk % 9;
  const int c0 = g * 16;
  const int W = (c0 + 16 <= NC) ? 16 : (NC - c0);
  const bool active = (col < W);
  const int cc = active ? (c0 + col) : (NC - 1);
  const int cp = col & 7;

  for (int i = t; i < 8 * 3 * 132; i += 256) ((float*)binacc)[i] = 0.f;

  const float2* simgA = s1 + (size_t)lp * (NDIM * NC);
  const float2* simgB = s1 + (size_t)(lp + pc) * (NDIM * NC);

  // ---- prefetch both images' columns + bin ids (hide HBM latency) ----------
  float xr[16], xi[16];      // image A column data
  float wr[16], wi[16];      // image B column data
#pragma unroll
  for (int n1 = 0; n1 < 16; ++n1) {
    const float2 v = simgA[(16 * n1 + sub) * NC + cc];
    xr[n1] = v.x; xi[n1] = v.y;
  }
#pragma unroll
  for (int n1 = 0; n1 < 16; ++n1) {
    const float2 v = simgB[(16 * n1 + sub) * NC + cc];
    wr[n1] = v.x; wi[n1] = v.y;
  }
  int bins[16];
#pragma unroll
  for (int k2 = 0; k2 < 16; ++k2) bins[k2] = rr[(sub + 16 * k2) * NC + cc];

  // ================= image A: column FFT, keep result in registers ==========
  float far[16], fai[16];
  {
    fft16(xr, xi);
#pragma unroll
    for (int k1 = 0; k1 < 16; ++k1) {
      float cw, sw; tw256(sub * k1, cw, sw);
      Bre[col * 290 + sub * 17 + k1] = xr[k1] * cw - xi[k1] * sw;
      Bim[col * 290 + sub * 17 + k1] = xr[k1] * sw + xi[k1] * cw;
    }
    __syncthreads();
#pragma unroll
    for (int n2 = 0; n2 < 16; ++n2) {
      far[n2] = Bre[col * 290 + n2 * 17 + sub];
      fai[n2] = Bim[col * 290 + n2 * 17 + sub];
    }
    fft16(far, fai);
    __syncthreads();
  }

  // ================= image B: column FFT + products + ring bins =============
  {
    fft16(wr, wi);
#pragma unroll
    for (int k1 = 0; k1 < 16; ++k1) {
      float cw, sw; tw256(sub * k1, cw, sw);
      Bre[col * 290 + sub * 17 + k1] = wr[k1] * cw - wi[k1] * sw;
      Bim[col * 290 + sub * 17 + k1] = wr[k1] * sw + wi[k1] * cw;
    }
    __syncthreads();
    float br[16], bi[16];
#pragma unroll
    for (int n2 = 0; n2 < 16; ++n2) {
      br[n2] = Bre[col * 290 + n2 * 17 + sub];
      bi[n2] = Bim[col * 290 + n2 * 17 + sub];
    }
    fft16(br, bi);
    if (active) {
#pragma unroll
      for (int k2 = 0; k2 < 16; ++k2) {
        const float pa = far[k2] * far[k2] + fai[k2] * fai[k2];
        const float pb = br[k2] * br[k2] + bi[k2] * bi[k2];
        const float nm = far[k2] * br[k2] + fai[k2] * bi[k2];
        atomicAdd(&binacc[cp][0][bins[k2]], pa);
        atomicAdd(&binacc[cp][1][bins[k2]], pb);
        atomicAdd(&binacc[cp][2][bins[k2]], nm);
      }
    }
    __syncthreads();
  }

  // per-(pair, group) partial ring sums (deterministic layout, no global atomics)
  float* pdst = partial + (size_t)((p0 + lp) * 9 + g) * (3 * NC);
  for (int i = t; i < 3 * NC; i += 256) {
    const int q = i / NC, bin = i % NC;
    float s = 0.f;
#pragma unroll
    for (int c = 0; c < 8; ++c) s += binacc[c][q][bin];
    pdst[i] = s;
  }
}

// ---------------- Stage 3a: per-pair FRC partial sum (double) ----------------
__global__ __launch_bounds__(128) void stage3a_kernel(
    const float* __restrict__ partial, double* __restrict__ pairsum) {
  const int pair = blockIdx.x;
  const int t = threadIdx.x;  // 128 threads; bins 1..126 active
  double v = 0.0;
  if (t >= 1 && t <= 126) {
    float na = 0.f, nb = 0.f, nm = 0.f;
    for (int g = 0; g < 9; ++g) {
      const float* p = partial + (size_t)(pair * 9 + g) * (3 * NC);
      na += p[t];
      nb += p[NC + t];
      nm += p[2 * NC + t];
    }
    const double den = fmax(sqrt((double)na) * sqrt((double)nb), 1e-4);
    v = (double)nm / den;
  }
  __shared__ double sd[128];
  sd[t] = v;
  __syncthreads();
  for (int s = 64; s > 0; s >>= 1) {
    if (t < s) sd[t] += sd[t + s];
    __syncthreads();
  }
  if (t == 0) pairsum[pair] = sd[0];
}

// ---------------- Stage 3b: final mean ---------------------------------------
__global__ __launch_bounds__(256) void stage3b_kernel(
    const double* __restrict__ pairsum, float* __restrict__ out) {
  const int t = threadIdx.x;
  __shared__ double sd[256];
  sd[t] = pairsum[t];
  __syncthreads();
  for (int s = 128; s > 0; s >>= 1) {
    if (t < s) sd[t] += sd[t + s];
    __syncthreads();
  }
  if (t == 0) out[0] = (float)(sd[0] / 32256.0);  // 256 pairs * 126 bins
}

extern "C" void kernel_launch(void* const* d_in, const int* in_sizes, int n_in,
                              void* d_out, int out_size, void* d_ws, size_t ws_size,
                              hipStream_t stream) {
  const float* a = (const float*)d_in[0];
  const float* b = (const float*)d_in[1];
  const int* rr = (const int*)d_in[2];
  float* out = (float*)d_out;

  char* ws = (char*)d_ws;
  const size_t partial_bytes = (size_t)NPAIRS * 9 * 3 * NC * sizeof(float);
  size_t off = (partial_bytes + 255) & ~(size_t)255;
  float* partial = (float*)ws;
  double* pairsum = (double*)(ws + off);
  off += ((size_t)NPAIRS * sizeof(double) + 255) & ~(size_t)255;
  float2* s1 = (float2*)(ws + off);

  const size_t bytes_per_img = (size_t)NDIM * NC * sizeof(float2);
  const size_t s1_avail = (ws_size > off) ? (ws_size - off) : 0;
  int cap = (int)(s1_avail / bytes_per_img);
  int P = cap / 2;
  if (P > NPAIRS) P = NPAIRS;
  if (P < 1) P = 1;  // assume workspace holds at least one pair

  for (int p0 = 0; p0 < NPAIRS; p0 += P) {
    const int pc = (NPAIRS - p0 < P) ? (NPAIRS - p0) : P;
    hipLaunchKernelGGL(stage1_kernel, dim3(4 * pc), dim3(256), 0, stream,
                       a, b, s1, p0, pc);
    hipLaunchKernelGGL(stage2_kernel, dim3(pc * 9), dim3(256), 0, stream,
                       s1, rr, partial, p0, pc);
  }
  hipLaunchKernelGGL(stage3a_kernel, dim3(NPAIRS), dim3(128), 0, stream,
                     partial, pairsum);
  hipLaunchKernelGGL(stage3b_kernel, dim3(1), dim3(256), 0, stream,
                     pairsum, out);
}